// Round 4
// baseline (770.449 us; speedup 1.0000x reference)
//
#include <hip/hip_runtime.h>
#include <hip/hip_cooperative_groups.h>
#include <cstdint>
#include <cstddef>

#define D 128

namespace cg = cooperative_groups;

typedef unsigned short ushort_t;
typedef unsigned int uint_t;
typedef __attribute__((ext_vector_type(8))) short bf16x8;
typedef __attribute__((ext_vector_type(4))) float f32x4;

static __device__ __forceinline__ unsigned short f2bf(float f) {
    unsigned int u = __float_as_uint(f);
    u = (u + 0x7FFFu + ((u >> 16) & 1u)) >> 16;  // RNE
    return (unsigned short)u;
}
static __device__ __forceinline__ float bf_lo(uint_t v) {
    return __uint_as_float(v << 16);
}
static __device__ __forceinline__ float bf_hi(uint_t v) {
    return __uint_as_float(v & 0xFFFF0000u);
}

static __device__ __forceinline__ void cast8(const float* __restrict__ s,
                                             ushort_t* __restrict__ d) {
    float4 a = *(const float4*)s;
    float4 b = *(const float4*)(s + 4);
    uint4 o;
    o.x = (uint_t)f2bf(a.x) | ((uint_t)f2bf(a.y) << 16);
    o.y = (uint_t)f2bf(a.z) | ((uint_t)f2bf(a.w) << 16);
    o.z = (uint_t)f2bf(b.x) | ((uint_t)f2bf(b.y) << 16);
    o.w = (uint_t)f2bf(b.z) | ((uint_t)f2bf(b.w) << 16);
    *(uint4*)d = o;
}

static __device__ __forceinline__ void acc8(uint4 v, float a[8]) {
    a[0] += bf_lo(v.x); a[1] += bf_hi(v.x);
    a[2] += bf_lo(v.y); a[3] += bf_hi(v.y);
    a[4] += bf_lo(v.z); a[5] += bf_hi(v.z);
    a[6] += bf_lo(v.w); a[7] += bf_hi(v.w);
}

static __device__ __forceinline__ uint4 grow(const ushort_t* __restrict__ xin,
                                             int s, int l16) {
    unsigned off = ((unsigned)s << 8) | ((unsigned)l16 << 4);  // bytes
    return *(const uint4*)((const char*)xin + off);
}

// ====================================================================
// Cooperative mega-kernel: all phases in one launch, grid.sync between.
// ====================================================================

struct MegaP {
    const float* x;
    const int* src;
    const int* dst;
    const float* W1l; const float* b1; const float* W1r;
    const float* W2l; const float* b2; const float* W2r;
    float* out;
    int* row_ptr; int* bhist; int* bcur; int* boff;
    int* ebuf; int* csr;
    ushort_t* xb; ushort_t* hb;
    ushort_t* W1lb; ushort_t* W1rb; ushort_t* W2lb; ushort_t* W2rb;
    int N, E, EB, NB, NT;
};

// sAgg row stride: 272 B (136 bf16) -> 16B-aligned rows; ds_read_b128 frag
// reads across 16 rows alias banks 2-way only (free per m136).
#define AGG_STRIDE_B 272

static __device__ __forceinline__ void layer_fused(
    const ushort_t* __restrict__ xin, const int* __restrict__ csr,
    const int* __restrict__ row_ptr, const ushort_t* __restrict__ Wl,
    const ushort_t* __restrict__ Wr, const float* __restrict__ bias,
    ushort_t* __restrict__ out_bf, float* __restrict__ out_f32,
    int N, int relu_bf, int NT,
    char* sac, ushort_t* sW, ushort_t* sX) {
    int tid = threadIdx.x;
    int wave = tid >> 6, lane = tid & 63;
    int g = lane >> 4, l16 = lane & 15;     // gather roles
    int quad = lane >> 4, l15 = lane & 15;  // mfma roles (same bits)
    int wm = wave & 1, wc = wave >> 1;
    int sr = tid >> 2;
    int sseg = (tid & 3) * 8;

    for (int tile = blockIdx.x; tile < NT; tile += gridDim.x) {
        __syncthreads();  // previous tile's LDS reads complete
        int n0 = tile * 128;

        // ---- aggregate 128 rows into sAgg; wave owns rows [wave*32, +32),
        //      2 nodes in flight (8 uint4 gathers outstanding) ----
        for (int i = 0; i < 32; i += 2) {
            int r0 = wave * 32 + i, r1 = r0 + 1;
            int node0 = min(n0 + r0, N - 1);
            int node1 = min(n0 + r1, N - 1);
            int b0 = row_ptr[node0];
            int deg0 = row_ptr[node0 + 1] - b0;
            int b1 = row_ptr[node1];
            int deg1 = row_ptr[node1 + 1] - b1;
            int d0 = min(deg0, 64), d1 = min(deg1, 64);
            int i0 = (deg0 > 0) ? csr[b0 + min(lane, deg0 - 1)] : 0;
            int i1 = (deg1 > 0) ? csr[b1 + min(lane, deg1 - 1)] : 0;
            int c0 = (d0 > 0 ? d0 : 1) - 1;
            int c1 = (d1 > 0 ? d1 : 1) - 1;
            float a0[8] = {0.f, 0.f, 0.f, 0.f, 0.f, 0.f, 0.f, 0.f};
            float a1[8] = {0.f, 0.f, 0.f, 0.f, 0.f, 0.f, 0.f, 0.f};
            int mm = max(d0, d1);
            for (int e = 0; e < mm; e += 16) {
                uint4 v0[4], v1[4];
#pragma unroll
                for (int q = 0; q < 4; ++q) {
                    int s = __shfl(i0, min(e + 4 * q + g, c0));
                    v0[q] = grow(xin, s, l16);
                }
#pragma unroll
                for (int q = 0; q < 4; ++q) {
                    int s = __shfl(i1, min(e + 4 * q + g, c1));
                    v1[q] = grow(xin, s, l16);
                }
#pragma unroll
                for (int q = 0; q < 4; ++q)
                    if (e + 4 * q + g < d0) acc8(v0[q], a0);
#pragma unroll
                for (int q = 0; q < 4; ++q)
                    if (e + 4 * q + g < d1) acc8(v1[q], a1);
            }
            for (int e2 = 64; e2 < deg0; e2 += 4) {  // rare deg>64
                int s = csr[b0 + min(e2 + g, deg0 - 1)];
                uint4 v = grow(xin, s, l16);
                if (e2 + g < deg0) acc8(v, a0);
            }
            for (int e2 = 64; e2 < deg1; e2 += 4) {
                int s = csr[b1 + min(e2 + g, deg1 - 1)];
                uint4 v = grow(xin, s, l16);
                if (e2 + g < deg1) acc8(v, a1);
            }
#pragma unroll
            for (int k = 0; k < 8; ++k) {
                a0[k] += __shfl_xor(a0[k], 16);
                a0[k] += __shfl_xor(a0[k], 32);
                a1[k] += __shfl_xor(a1[k], 16);
                a1[k] += __shfl_xor(a1[k], 32);
            }
            if (g == 0) {
                float inv0 = 1.0f / fmaxf((float)deg0, 1.0f);
                uint4 o0;
                o0.x = (uint_t)f2bf(a0[0] * inv0) | ((uint_t)f2bf(a0[1] * inv0) << 16);
                o0.y = (uint_t)f2bf(a0[2] * inv0) | ((uint_t)f2bf(a0[3] * inv0) << 16);
                o0.z = (uint_t)f2bf(a0[4] * inv0) | ((uint_t)f2bf(a0[5] * inv0) << 16);
                o0.w = (uint_t)f2bf(a0[6] * inv0) | ((uint_t)f2bf(a0[7] * inv0) << 16);
                *(uint4*)(sac + r0 * AGG_STRIDE_B + l16 * 16) = o0;
                float inv1 = 1.0f / fmaxf((float)deg1, 1.0f);
                uint4 o1;
                o1.x = (uint_t)f2bf(a1[0] * inv1) | ((uint_t)f2bf(a1[1] * inv1) << 16);
                o1.y = (uint_t)f2bf(a1[2] * inv1) | ((uint_t)f2bf(a1[3] * inv1) << 16);
                o1.z = (uint_t)f2bf(a1[4] * inv1) | ((uint_t)f2bf(a1[5] * inv1) << 16);
                o1.w = (uint_t)f2bf(a1[6] * inv1) | ((uint_t)f2bf(a1[7] * inv1) << 16);
                *(uint4*)(sac + r1 * AGG_STRIDE_B + l16 * 16) = o1;
            }
        }

        // ---- GEMM: [sAgg | xin_rows] @ [Wl | Wr]^T + bias ----
        f32x4 acc[4][4];
#pragma unroll
        for (int mt = 0; mt < 4; ++mt)
#pragma unroll
            for (int nt = 0; nt < 4; ++nt) acc[mt][nt] = (f32x4){0.f, 0.f, 0.f, 0.f};

        int ga0 = min(n0 + sr, N - 1);
        int ga1 = min(n0 + sr + 64, N - 1);

#pragma unroll
        for (int c = 0; c < 8; ++c) {
            const ushort_t* Wb = (c < 4) ? Wl : Wr;
            int koff = (c & 3) * 32 + sseg;
            bf16x8 vw0 = *(const bf16x8*)(Wb + (size_t)sr * D + koff);
            bf16x8 vw1 = *(const bf16x8*)(Wb + (size_t)(sr + 64) * D + koff);
            bf16x8 va0, va1;
            if (c >= 4) {
                va0 = *(const bf16x8*)(xin + (size_t)ga0 * D + koff);
                va1 = *(const bf16x8*)(xin + (size_t)ga1 * D + koff);
            }
            __syncthreads();  // prev chunk consumed; (c==0) also fences agg writes
            *(bf16x8*)&sW[sr * 32 + sseg] = vw0;
            *(bf16x8*)&sW[(sr + 64) * 32 + sseg] = vw1;
            if (c >= 4) {
                *(bf16x8*)&sX[sr * 32 + sseg] = va0;
                *(bf16x8*)&sX[(sr + 64) * 32 + sseg] = va1;
            }
            __syncthreads();

            bf16x8 af[4], wf[4];
#pragma unroll
            for (int mt = 0; mt < 4; ++mt) {
                int row = wm * 64 + mt * 16 + l15;
                af[mt] = (c < 4)
                    ? *(const bf16x8*)(sac + row * AGG_STRIDE_B + ((c & 3) * 32 + quad * 8) * 2)
                    : *(const bf16x8*)&sX[row * 32 + quad * 8];
            }
#pragma unroll
            for (int nt = 0; nt < 4; ++nt)
                wf[nt] = *(const bf16x8*)&sW[(wc * 64 + nt * 16 + l15) * 32 + quad * 8];
#pragma unroll
            for (int mt = 0; mt < 4; ++mt)
#pragma unroll
                for (int nt = 0; nt < 4; ++nt)
                    acc[mt][nt] = __builtin_amdgcn_mfma_f32_16x16x32_bf16(
                        af[mt], wf[nt], acc[mt][nt], 0, 0, 0);
        }

#pragma unroll
        for (int mt = 0; mt < 4; ++mt) {
#pragma unroll
            for (int nt = 0; nt < 4; ++nt) {
                int col = wc * 64 + nt * 16 + l15;
                float bv = bias[col];
#pragma unroll
                for (int reg = 0; reg < 4; ++reg) {
                    int row = n0 + wm * 64 + mt * 16 + quad * 4 + reg;
                    if (row < N) {
                        float v = acc[mt][nt][reg] + bv;
                        if (relu_bf) {
                            v = fmaxf(v, 0.f);
                            out_bf[(size_t)row * D + col] = f2bf(v);
                        } else {
                            out_f32[(size_t)row * D + col] = v;
                        }
                    }
                }
            }
        }
    }
}

__global__ __launch_bounds__(256, 3) void mega(MegaP P) {
    __shared__ ushort_t sAgg[128 * 136];  // 34816 B (272 B/row)
    __shared__ ushort_t sW[128 * 32];     // 8192 B
    __shared__ ushort_t sX[128 * 32];     // 8192 B
    int* si = (int*)sAgg;                 // alias for CSR phases
    char* sac = (char*)sAgg;
    cg::grid_group gg = cg::this_grid();
    int t = threadIdx.x, bid = blockIdx.x, gsz = gridDim.x;
    int N = P.N, E = P.E;

    // ---- P0: zero bucket histogram ----
    for (int i = bid * 256 + t; i < 1024; i += gsz * 256) P.bhist[i] = 0;
    gg.sync();

    // ---- P1: bucket histogram + fp32->bf16 casts (independent work) ----
    for (int chunk = bid; chunk < P.EB; chunk += gsz) {
        si[t] = 0;
        si[t + 256] = 0;
        __syncthreads();
        int base = chunk * 4096;
#pragma unroll
        for (int k = 0; k < 16; ++k) {
            int e = base + k * 256 + t;
            if (e < E) atomicAdd(&si[P.dst[e] >> 8], 1);
        }
        __syncthreads();
        if (si[t]) atomicAdd(&P.bhist[t], si[t]);
        if (si[t + 256]) atomicAdd(&P.bhist[t + 256], si[t + 256]);
        __syncthreads();
    }
    {
        int items = (N * D) >> 3;
        for (int i = bid * 256 + t; i < items; i += gsz * 256)
            cast8(P.x + (size_t)i * 8, P.xb + (size_t)i * 8);
        for (int i = bid * 256 + t; i < 4 * 2048; i += gsz * 256) {
            int arr = i >> 11;
            int j = (i & 2047) * 8;
            const float* s = (arr == 0) ? P.W1l : (arr == 1) ? P.W1r
                           : (arr == 2) ? P.W2l : P.W2r;
            ushort_t* d = (arr == 0) ? P.W1lb : (arr == 1) ? P.W1rb
                        : (arr == 2) ? P.W2lb : P.W2rb;
            cast8(s + j, d + j);
        }
    }
    gg.sync();

    // ---- P2: exclusive scan of 512 buckets (block 0; 2 elems/thread) ----
    if (bid == 0) {
        int a0 = P.bhist[2 * t], a1 = P.bhist[2 * t + 1];
        int ps = a0 + a1;
        si[t] = ps;
        __syncthreads();
        for (int off = 1; off < 256; off <<= 1) {
            int u = (t >= off) ? si[t - off] : 0;
            __syncthreads();
            si[t] += u;
            __syncthreads();
        }
        int inc = si[t];
        int exb = inc - ps;
        P.boff[2 * t] = exb;
        P.bcur[2 * t] = exb;
        P.boff[2 * t + 1] = exb + a0;
        P.bcur[2 * t + 1] = exb + a0;
        if (t == 255) P.boff[512] = inc;
        if (t == 0) P.row_ptr[N] = E;
    }
    gg.sync();

    // ---- P3: scatter edges into buckets ----
    for (int chunk = bid; chunk < P.EB; chunk += gsz) {
        si[t] = 0;
        si[t + 256] = 0;
        __syncthreads();
        int base = chunk * 4096;
        unsigned pk[16];  // rank<<17 | bkt<<8 | dlocal
#pragma unroll
        for (int k = 0; k < 16; ++k) {
            int e = base + k * 256 + t;
            unsigned p = 0xFFFFFFFFu;
            if (e < E) {
                int d = P.dst[e];
                int bkt = d >> 8;
                int r = atomicAdd(&si[bkt], 1);
                p = ((unsigned)r << 17) | ((unsigned)bkt << 8) | (unsigned)(d & 255);
            }
            pk[k] = p;
        }
        __syncthreads();
        if (si[t]) si[512 + t] = atomicAdd(&P.bcur[t], si[t]);
        if (si[t + 256]) si[512 + t + 256] = atomicAdd(&P.bcur[t + 256], si[t + 256]);
        __syncthreads();
#pragma unroll
        for (int k = 0; k < 16; ++k) {
            int e = base + k * 256 + t;
            if (e < E) {
                unsigned p = pk[k];
                int bkt = (p >> 8) & 511;
                int r = (int)(p >> 17);
                P.ebuf[si[512 + bkt] + r] = P.src[e] | ((int)(p & 255) << 20);
            }
        }
        __syncthreads();
    }
    gg.sync();

    // ---- P4: build per-node CSR within each bucket ----
    for (int b = bid; b < P.NB; b += gsz) {
        int base = b << 8;
        int ebeg = P.boff[b], eend = P.boff[b + 1];
        si[t] = 0;  // lcnt
        __syncthreads();
        for (int e = ebeg + t; e < eend; e += 256)
            atomicAdd(&si[((unsigned)P.ebuf[e]) >> 20], 1);
        __syncthreads();
        int v = si[t];
        si[256 + t] = v;  // lofs
        __syncthreads();
        for (int off = 1; off < 256; off <<= 1) {
            int u = (t >= off) ? si[256 + t - off] : 0;
            __syncthreads();
            si[256 + t] += u;
            __syncthreads();
        }
        int ex = si[256 + t] - v;
        __syncthreads();
        si[256 + t] = ex;
        si[512 + t] = 0;  // lcur
        if (base + t < N) P.row_ptr[base + t] = ebeg + ex;
        __syncthreads();
        for (int e = ebeg + t; e < eend; e += 256) {
            int u = P.ebuf[e];
            int d = ((unsigned)u) >> 20;
            int r = atomicAdd(&si[512 + d], 1);
            P.csr[ebeg + si[256 + d] + r] = u & 0xFFFFF;
        }
        __syncthreads();
    }
    gg.sync();

    // ---- P5: layer 1 (agg + gemm fused per 128-node tile) ----
    layer_fused(P.xb, P.csr, P.row_ptr, P.W1lb, P.W1rb, P.b1,
                P.hb, nullptr, N, 1, P.NT, sac, sW, sX);
    gg.sync();

    // ---- P6: layer 2 ----
    layer_fused(P.hb, P.csr, P.row_ptr, P.W2lb, P.W2rb, P.b2,
                nullptr, P.out, N, 0, P.NT, sac, sW, sX);
}

// ====================================================================
// Fallback path (R1-best multi-kernel) in case cooperative launch fails
// ====================================================================

__global__ __launch_bounds__(256) void bkt_hist(const int* __restrict__ dst,
                                                int* __restrict__ bhist, int E) {
    __shared__ int lh[512];
    int t = threadIdx.x;
    lh[t] = 0;
    lh[t + 256] = 0;
    __syncthreads();
    int base = blockIdx.x * 4096;
#pragma unroll
    for (int i = 0; i < 16; ++i) {
        int e = base + i * 256 + t;
        if (e < E) atomicAdd(&lh[dst[e] >> 8], 1);
    }
    __syncthreads();
    if (lh[t]) atomicAdd(&bhist[t], lh[t]);
    if (lh[t + 256]) atomicAdd(&bhist[t + 256], lh[t + 256]);
}

__global__ __launch_bounds__(512) void bkt_scan(const int* __restrict__ bhist,
                                                int* __restrict__ boff,
                                                int* __restrict__ bcur,
                                                int* __restrict__ row_ptr,
                                                int N, int E) {
    __shared__ int s[512];
    int t = threadIdx.x;
    int v = bhist[t];
    s[t] = v;
    __syncthreads();
    for (int off = 1; off < 512; off <<= 1) {
        int u = (t >= off) ? s[t - off] : 0;
        __syncthreads();
        s[t] += u;
        __syncthreads();
    }
    int ex = s[t] - v;
    boff[t] = ex;
    bcur[t] = ex;
    if (t == 511) boff[512] = s[511];
    if (t == 0) row_ptr[N] = E;
}

__global__ __launch_bounds__(256) void bkt_scatter(const int* __restrict__ src,
                                                   const int* __restrict__ dst,
                                                   int* __restrict__ bcur,
                                                   int* __restrict__ ebuf, int E) {
    __shared__ int lh[512];
    __shared__ int gb[512];
    int t = threadIdx.x;
    lh[t] = 0;
    lh[t + 256] = 0;
    __syncthreads();
    int base = blockIdx.x * 4096;
    unsigned pk[16];
#pragma unroll
    for (int i = 0; i < 16; ++i) {
        int e = base + i * 256 + t;
        unsigned p = 0xFFFFFFFFu;
        if (e < E) {
            int d = dst[e];
            int bkt = d >> 8;
            int r = atomicAdd(&lh[bkt], 1);
            p = ((unsigned)r << 17) | ((unsigned)bkt << 8) | (unsigned)(d & 255);
        }
        pk[i] = p;
    }
    __syncthreads();
    if (lh[t]) gb[t] = atomicAdd(&bcur[t], lh[t]);
    if (lh[t + 256]) gb[t + 256] = atomicAdd(&bcur[t + 256], lh[t + 256]);
    __syncthreads();
#pragma unroll
    for (int i = 0; i < 16; ++i) {
        int e = base + i * 256 + t;
        if (e < E) {
            unsigned p = pk[i];
            int bkt = (p >> 8) & 511;
            int r = (int)(p >> 17);
            ebuf[gb[bkt] + r] = src[e] | ((int)(p & 255) << 20);
        }
    }
}

__global__ __launch_bounds__(256) void bkt_build(const int* __restrict__ ebuf,
                                                 const int* __restrict__ boff,
                                                 int* __restrict__ row_ptr,
                                                 int* __restrict__ csr, int N) {
    __shared__ int lcnt[256];
    __shared__ int lofs[256];
    __shared__ int lcur[256];
    int t = threadIdx.x;
    int b = blockIdx.x;
    int base = b << 8;
    int ebeg = boff[b], eend = boff[b + 1];
    lcnt[t] = 0;
    __syncthreads();
    for (int e = ebeg + t; e < eend; e += 256)
        atomicAdd(&lcnt[((unsigned)ebuf[e]) >> 20], 1);
    __syncthreads();
    int v = lcnt[t];
    lofs[t] = v;
    __syncthreads();
    for (int off = 1; off < 256; off <<= 1) {
        int u = (t >= off) ? lofs[t - off] : 0;
        __syncthreads();
        lofs[t] += u;
        __syncthreads();
    }
    int ex = lofs[t] - v;
    __syncthreads();
    lofs[t] = ex;
    lcur[t] = 0;
    if (base + t < N) row_ptr[base + t] = ebeg + ex;
    __syncthreads();
    for (int e = ebeg + t; e < eend; e += 256) {
        int u = ebuf[e];
        int d = ((unsigned)u) >> 20;
        int r = atomicAdd(&lcur[d], 1);
        csr[ebeg + lofs[d] + r] = u & 0xFFFFF;
    }
}

__global__ __launch_bounds__(256) void cast_x_kernel(const float* __restrict__ src,
                                                     ushort_t* __restrict__ dst,
                                                     long n) {
    long i = ((long)blockIdx.x * 256 + threadIdx.x) * 8;
    if (i >= n) return;
    cast8(src + i, dst + i);
}

__global__ __launch_bounds__(256) void cast_w_kernel(const float* __restrict__ s0,
                                                     const float* __restrict__ s1,
                                                     const float* __restrict__ s2,
                                                     const float* __restrict__ s3,
                                                     ushort_t* __restrict__ d0,
                                                     ushort_t* __restrict__ d1,
                                                     ushort_t* __restrict__ d2,
                                                     ushort_t* __restrict__ d3) {
    const float* s = (blockIdx.y == 0) ? s0 : (blockIdx.y == 1) ? s1
                   : (blockIdx.y == 2) ? s2 : s3;
    ushort_t* d = (blockIdx.y == 0) ? d0 : (blockIdx.y == 1) ? d1
                : (blockIdx.y == 2) ? d2 : d3;
    long i = ((long)blockIdx.x * 256 + threadIdx.x) * 8;
    cast8(s + i, d + i);
}

__global__ __launch_bounds__(256) void agg_b_kernel(const ushort_t* __restrict__ xin,
                                                    const int* __restrict__ csr,
                                                    const int* __restrict__ row_ptr,
                                                    ushort_t* __restrict__ aggb, int N) {
    int node = blockIdx.x * 4 + (threadIdx.x >> 6);
    if (node >= N) return;
    int lane = threadIdx.x & 63;
    int g = lane >> 4;
    int l16 = lane & 15;
    int beg = row_ptr[node], end = row_ptr[node + 1];
    int deg = end - beg;
    float a[8] = {0.f, 0.f, 0.f, 0.f, 0.f, 0.f, 0.f, 0.f};

    if (deg > 0) {
        int deg64 = min(deg, 64);
        int myidx = csr[beg + min(lane, deg - 1)];
        int e = 0;
        for (; e + 16 <= deg64; e += 16) {
            int s0 = __shfl(myidx, e + g);
            int s1 = __shfl(myidx, e + 4 + g);
            int s2 = __shfl(myidx, e + 8 + g);
            int s3 = __shfl(myidx, e + 12 + g);
            uint4 v0 = grow(xin, s0, l16);
            uint4 v1 = grow(xin, s1, l16);
            uint4 v2 = grow(xin, s2, l16);
            uint4 v3 = grow(xin, s3, l16);
            acc8(v0, a); acc8(v1, a); acc8(v2, a); acc8(v3, a);
        }
        if (e + 8 <= deg64) {
            int s0 = __shfl(myidx, e + g);
            int s1 = __shfl(myidx, e + 4 + g);
            uint4 v0 = grow(xin, s0, l16);
            uint4 v1 = grow(xin, s1, l16);
            acc8(v0, a); acc8(v1, a);
            e += 8;
        }
        if (e + 4 <= deg64) {
            int s0 = __shfl(myidx, e + g);
            uint4 v0 = grow(xin, s0, l16);
            acc8(v0, a);
            e += 4;
        }
        if (e < deg64) {
            int ee = min(e + g, deg64 - 1);
            int s = __shfl(myidx, ee);
            uint4 v = grow(xin, s, l16);
            if (e + g < deg64) acc8(v, a);
        }
        for (int e2 = 64; e2 < deg; e2 += 4) {
            int s = csr[beg + min(e2 + g, deg - 1)];
            uint4 v = grow(xin, s, l16);
            if (e2 + g < deg) acc8(v, a);
        }
    }

#pragma unroll
    for (int i = 0; i < 8; ++i) {
        a[i] += __shfl_xor(a[i], 16);
        a[i] += __shfl_xor(a[i], 32);
    }
    if (g == 0) {
        float inv = 1.0f / fmaxf((float)deg, 1.0f);
        uint4 o;
        o.x = (uint_t)f2bf(a[0] * inv) | ((uint_t)f2bf(a[1] * inv) << 16);
        o.y = (uint_t)f2bf(a[2] * inv) | ((uint_t)f2bf(a[3] * inv) << 16);
        o.z = (uint_t)f2bf(a[4] * inv) | ((uint_t)f2bf(a[5] * inv) << 16);
        o.w = (uint_t)f2bf(a[6] * inv) | ((uint_t)f2bf(a[7] * inv) << 16);
        unsigned off = ((unsigned)node << 8) | ((unsigned)l16 << 4);
        *(uint4*)((char*)aggb + off) = o;
    }
}

__global__ __launch_bounds__(256) void gemm_mfma(const ushort_t* __restrict__ Aagg,
                                                 const ushort_t* __restrict__ Ax,
                                                 const ushort_t* __restrict__ Wl,
                                                 const ushort_t* __restrict__ Wr,
                                                 const float* __restrict__ bias,
                                                 ushort_t* __restrict__ out_bf,
                                                 float* __restrict__ out_f32,
                                                 int N, int relu_bf) {
    __shared__ ushort_t sA[128 * 32];
    __shared__ ushort_t sW[128 * 32];
    int tid = threadIdx.x;
    int wave = tid >> 6, lane = tid & 63;
    int quad = lane >> 4, l15 = lane & 15;
    int wm = wave & 1, wc = wave >> 1;
    int n0 = blockIdx.x * 128;
    int sr = tid >> 2;
    int sseg = (tid & 3) * 8;

    f32x4 acc[4][4];
#pragma unroll
    for (int mt = 0; mt < 4; ++mt)
#pragma unroll
        for (int nt = 0; nt < 4; ++nt) acc[mt][nt] = (f32x4){0.f, 0.f, 0.f, 0.f};

    int ga0 = min(n0 + sr, N - 1);
    int ga1 = min(n0 + sr + 64, N - 1);

#pragma unroll
    for (int c = 0; c < 8; ++c) {
        const ushort_t* Ab = (c < 4) ? Aagg : Ax;
        const ushort_t* Wb = (c < 4) ? Wl : Wr;
        int koff = (c & 3) * 32 + sseg;
        bf16x8 va0 = *(const bf16x8*)(Ab + (size_t)ga0 * D + koff);
        bf16x8 va1 = *(const bf16x8*)(Ab + (size_t)ga1 * D + koff);
        bf16x8 vw0 = *(const bf16x8*)(Wb + (size_t)sr * D + koff);
        bf16x8 vw1 = *(const bf16x8*)(Wb + (size_t)(sr + 64) * D + koff);
        __syncthreads();
        *(bf16x8*)&sA[sr * 32 + sseg] = va0;
        *(bf16x8*)&sA[(sr + 64) * 32 + sseg] = va1;
        *(bf16x8*)&sW[sr * 32 + sseg] = vw0;
        *(bf16x8*)&sW[(sr + 64) * 32 + sseg] = vw1;
        __syncthreads();

        bf16x8 af[4], wf[4];
#pragma unroll
        for (int mt = 0; mt < 4; ++mt)
            af[mt] = *(const bf16x8*)&sA[(wm * 64 + mt * 16 + l15) * 32 + quad * 8];
#pragma unroll
        for (int nt = 0; nt < 4; ++nt)
            wf[nt] = *(const bf16x8*)&sW[(wc * 64 + nt * 16 + l15) * 32 + quad * 8];
#pragma unroll
        for (int mt = 0; mt < 4; ++mt)
#pragma unroll
            for (int nt = 0; nt < 4; ++nt)
                acc[mt][nt] = __builtin_amdgcn_mfma_f32_16x16x32_bf16(
                    af[mt], wf[nt], acc[mt][nt], 0, 0, 0);
    }

#pragma unroll
    for (int mt = 0; mt < 4; ++mt) {
#pragma unroll
        for (int nt = 0; nt < 4; ++nt) {
            int col = wc * 64 + nt * 16 + l15;
            float bv = bias[col];
#pragma unroll
            for (int reg = 0; reg < 4; ++reg) {
                int row = n0 + wm * 64 + mt * 16 + quad * 4 + reg;
                if (row < N) {
                    float v = acc[mt][nt][reg] + bv;
                    if (relu_bf) {
                        v = fmaxf(v, 0.f);
                        out_bf[(size_t)row * D + col] = f2bf(v);
                    } else {
                        out_f32[(size_t)row * D + col] = v;
                    }
                }
            }
        }
    }
}

// ================= launch =================

extern "C" void kernel_launch(void* const* d_in, const int* in_sizes, int n_in,
                              void* d_out, int out_size, void* d_ws, size_t ws_size,
                              hipStream_t stream) {
    const float* x   = (const float*)d_in[0];
    const int*   ei  = (const int*)d_in[1];
    const float* W1l = (const float*)d_in[2];
    const float* b1  = (const float*)d_in[3];
    const float* W1r = (const float*)d_in[4];
    const float* W2l = (const float*)d_in[5];
    const float* b2  = (const float*)d_in[6];
    const float* W2r = (const float*)d_in[7];
    float* out = (float*)d_out;

    int N = in_sizes[0] / D;
    int E = in_sizes[1] / 2;
    const int* src = ei;
    const int* dst = ei + E;

    char* ws = (char*)d_ws;
    size_t off = 0;
    auto take = [&](size_t bytes) -> char* {
        char* p = ws + off;
        off += (bytes + 255) & ~(size_t)255;
        return p;
    };
    int*      row_ptr = (int*)take((size_t)(N + 1) * sizeof(int));
    int*      bhist   = (int*)take((size_t)(512 + 512 + 513) * sizeof(int));
    int*      bcur    = bhist + 512;
    int*      boff    = bhist + 1024;
    int*      ebuf    = (int*)take((size_t)E * sizeof(int));
    int*      csr     = (int*)take((size_t)E * sizeof(int));
    ushort_t* xb      = (ushort_t*)take((size_t)N * D * sizeof(ushort_t));
    ushort_t* hb      = (ushort_t*)take((size_t)N * D * sizeof(ushort_t));
    ushort_t* aggb    = (ushort_t*)take((size_t)N * D * sizeof(ushort_t));
    ushort_t* W1lb    = (ushort_t*)take((size_t)D * D * sizeof(ushort_t));
    ushort_t* W1rb    = (ushort_t*)take((size_t)D * D * sizeof(ushort_t));
    ushort_t* W2lb    = (ushort_t*)take((size_t)D * D * sizeof(ushort_t));
    ushort_t* W2rb    = (ushort_t*)take((size_t)D * D * sizeof(ushort_t));
    (void)ws_size;
    (void)n_in;
    (void)out_size;

    MegaP P;
    P.x = x; P.src = src; P.dst = dst;
    P.W1l = W1l; P.b1 = b1; P.W1r = W1r;
    P.W2l = W2l; P.b2 = b2; P.W2r = W2r;
    P.out = out;
    P.row_ptr = row_ptr; P.bhist = bhist; P.bcur = bcur; P.boff = boff;
    P.ebuf = ebuf; P.csr = csr;
    P.xb = xb; P.hb = hb;
    P.W1lb = W1lb; P.W1rb = W1rb; P.W2lb = W2lb; P.W2rb = W2rb;
    P.N = N; P.E = E;
    P.EB = (E + 4095) / 4096;
    P.NB = (N + 255) / 256;
    P.NT = (N + 127) / 128;

    static int s_grid = 0;
    if (s_grid == 0) {
        int maxB = 0;
        hipOccupancyMaxActiveBlocksPerMultiprocessor(&maxB, mega, 256, 0);
        int dev = 0, numCU = 0;
        hipGetDevice(&dev);
        hipDeviceGetAttribute(&numCU, hipDeviceAttributeMultiprocessorCount, dev);
        if (maxB < 1) maxB = 1;
        if (numCU < 1) numCU = 256;
        long g = (long)maxB * numCU;
        if (g > 2048) g = 2048;
        s_grid = (int)g;
    }

    void* kp[] = {(void*)&P};
    hipError_t err = hipLaunchCooperativeKernel((void*)mega, dim3(s_grid),
                                                dim3(256), kp, 0, stream);
    if (err != hipSuccess) {
        // -------- fallback: proven multi-kernel path --------
        hipMemsetAsync(bhist, 0, 1024 * sizeof(int), stream);
        int NB = (N + 255) / 256;
        int EB = (E + 4095) / 4096;
        bkt_hist<<<EB, 256, 0, stream>>>(dst, bhist, E);
        bkt_scan<<<1, 512, 0, stream>>>(bhist, boff, bcur, row_ptr, N, E);
        bkt_scatter<<<EB, 256, 0, stream>>>(src, dst, bcur, ebuf, E);
        bkt_build<<<NB, 256, 0, stream>>>(ebuf, boff, row_ptr, csr, N);
        long nx = (long)N * D;
        cast_x_kernel<<<(int)((nx / 8 + 255) / 256), 256, 0, stream>>>(x, xb, nx);
        cast_w_kernel<<<dim3(8, 4), 256, 0, stream>>>(W1l, W1r, W2l, W2r,
                                                      W1lb, W1rb, W2lb, W2rb);
        int ablocks = (N + 3) / 4;
        int gblocks = (N + 127) / 128;
        agg_b_kernel<<<ablocks, 256, 0, stream>>>(xb, csr, row_ptr, aggb, N);
        gemm_mfma<<<gblocks, 256, 0, stream>>>(aggb, xb, W1lb, W1rb, b1, hb, nullptr, N, 1);
        agg_b_kernel<<<ablocks, 256, 0, stream>>>(hb, csr, row_ptr, aggb, N);
        gemm_mfma<<<gblocks, 256, 0, stream>>>(aggb, hb, W2lb, W2rb, b2, nullptr, out, N, 0);
    }
}

// Round 5
// 336.365 us; speedup vs baseline: 2.2905x; 2.2905x over previous
//
#include <hip/hip_runtime.h>
#include <cstdint>
#include <cstddef>

#define D 128

typedef unsigned short ushort_t;
typedef unsigned int uint_t;
typedef __attribute__((ext_vector_type(8))) short bf16x8;
typedef __attribute__((ext_vector_type(4))) float f32x4;

static __device__ __forceinline__ unsigned short f2bf(float f) {
    unsigned int u = __float_as_uint(f);
    u = (u + 0x7FFFu + ((u >> 16) & 1u)) >> 16;  // RNE
    return (unsigned short)u;
}
static __device__ __forceinline__ float bf_lo(uint_t v) {
    return __uint_as_float(v << 16);
}
static __device__ __forceinline__ float bf_hi(uint_t v) {
    return __uint_as_float(v & 0xFFFF0000u);
}

static __device__ __forceinline__ void cast8(const float* __restrict__ s,
                                             ushort_t* __restrict__ d) {
    float4 a = *(const float4*)s;
    float4 b = *(const float4*)(s + 4);
    uint4 o;
    o.x = (uint_t)f2bf(a.x) | ((uint_t)f2bf(a.y) << 16);
    o.y = (uint_t)f2bf(a.z) | ((uint_t)f2bf(a.w) << 16);
    o.z = (uint_t)f2bf(b.x) | ((uint_t)f2bf(b.y) << 16);
    o.w = (uint_t)f2bf(b.z) | ((uint_t)f2bf(b.w) << 16);
    *(uint4*)d = o;
}

// ================= fused front-end: bkt_hist + cast_x + cast_w =================
// blocks [0,EB): edge-bucket histogram; [EB,EB+CX): x cast; [EB+CX,+32): W casts.
// Independent work co-scheduled: hist is atomic/latency-bound, casts BW-bound.

__global__ __launch_bounds__(256) void front_fused(
    const int* __restrict__ dst, int* __restrict__ bhist, int E, int EB,
    const float* __restrict__ x, ushort_t* __restrict__ xb, long nx, int CX,
    const float* __restrict__ W1l, const float* __restrict__ W1r,
    const float* __restrict__ W2l, const float* __restrict__ W2r,
    ushort_t* __restrict__ W1lb, ushort_t* __restrict__ W1rb,
    ushort_t* __restrict__ W2lb, ushort_t* __restrict__ W2rb) {
    __shared__ int lh[512];
    int b = blockIdx.x, t = threadIdx.x;
    if (b < EB) {
        lh[t] = 0;
        lh[t + 256] = 0;
        __syncthreads();
        int base = b * 4096;
#pragma unroll
        for (int i = 0; i < 16; ++i) {
            int e = base + i * 256 + t;
            if (e < E) atomicAdd(&lh[dst[e] >> 8], 1);
        }
        __syncthreads();
        if (lh[t]) atomicAdd(&bhist[t], lh[t]);
        if (lh[t + 256]) atomicAdd(&bhist[t + 256], lh[t + 256]);
    } else if (b < EB + CX) {
        long i = ((long)(b - EB) * 256 + t) * 8;
        if (i < nx) cast8(x + i, xb + i);
    } else {
        int bb = b - EB - CX;  // 0..31; 8 blocks per weight array
        int arr = bb >> 3;
        long i = ((long)(bb & 7) * 256 + t) * 8;  // < 16384
        const float* s = (arr == 0) ? W1l : (arr == 1) ? W1r
                       : (arr == 2) ? W2l : W2r;
        ushort_t* d = (arr == 0) ? W1lb : (arr == 1) ? W1rb
                    : (arr == 2) ? W2lb : W2rb;
        cast8(s + i, d + i);
    }
}

// ================= CSR build =================

__global__ __launch_bounds__(512) void bkt_scan(const int* __restrict__ bhist,
                                                int* __restrict__ boff,
                                                int* __restrict__ bcur,
                                                int* __restrict__ row_ptr,
                                                int N, int E) {
    __shared__ int s[512];
    int t = threadIdx.x;
    int v = bhist[t];
    s[t] = v;
    __syncthreads();
    for (int off = 1; off < 512; off <<= 1) {
        int u = (t >= off) ? s[t - off] : 0;
        __syncthreads();
        s[t] += u;
        __syncthreads();
    }
    int ex = s[t] - v;
    boff[t] = ex;
    bcur[t] = ex;
    if (t == 511) boff[512] = s[511];
    if (t == 0) row_ptr[N] = E;
}

// LDS-sorted scatter: edges placed bucket-sorted in LDS, then written out so
// consecutive lanes hit consecutive addresses within each bucket run
// (coalesced ~32B chunks instead of 4B random scatter -> ~4-8x fewer HBM
// write transactions).
__global__ __launch_bounds__(256) void bkt_scatter(const int* __restrict__ src,
                                                   const int* __restrict__ dst,
                                                   int* __restrict__ bcur,
                                                   int* __restrict__ ebuf, int E) {
    __shared__ int lh[512];
    __shared__ int lofs[512];
    __shared__ int gb[512];
    __shared__ int sv[4096];
    __shared__ unsigned short sb[4096];
    int t = threadIdx.x;
    lh[t] = 0;
    lh[t + 256] = 0;
    __syncthreads();
    int base = blockIdx.x * 4096;
    unsigned pk[16];  // rank<<17 | bkt<<8 | dlocal
#pragma unroll
    for (int i = 0; i < 16; ++i) {
        int e = base + i * 256 + t;
        unsigned p = 0xFFFFFFFFu;
        if (e < E) {
            int d = dst[e];
            int bkt = d >> 8;
            int r = atomicAdd(&lh[bkt], 1);
            p = ((unsigned)r << 17) | ((unsigned)bkt << 8) | (unsigned)(d & 255);
        }
        pk[i] = p;
    }
    __syncthreads();
    // block-level exclusive scan of lh[0..511], 2 buckets/thread (gb = temp)
    int a0 = lh[2 * t], a1 = lh[2 * t + 1];
    int ps = a0 + a1;
    gb[t] = ps;
    __syncthreads();
    for (int off = 1; off < 256; off <<= 1) {
        int u = (t >= off) ? gb[t - off] : 0;
        __syncthreads();
        gb[t] += u;
        __syncthreads();
    }
    int inc = gb[t];
    int exb = inc - ps;
    __syncthreads();
    lofs[2 * t] = exb;
    lofs[2 * t + 1] = exb + a0;
    if (a0) gb[2 * t] = atomicAdd(&bcur[2 * t], a0);
    if (a1) gb[2 * t + 1] = atomicAdd(&bcur[2 * t + 1], a1);
    __syncthreads();
    // place edges bucket-sorted into LDS
#pragma unroll
    for (int i = 0; i < 16; ++i) {
        int e = base + i * 256 + t;
        if (e < E) {
            unsigned p = pk[i];
            int bkt = (p >> 8) & 511;
            int r = (int)(p >> 17);
            int pos = lofs[bkt] + r;
            sv[pos] = src[e] | ((int)(p & 255) << 20);
            sb[pos] = (unsigned short)bkt;
        }
    }
    __syncthreads();
    // coalesced write-out
    int cnt = min(E - base, 4096);
    for (int i = t; i < cnt; i += 256) {
        int b2 = sb[i];
        ebuf[gb[b2] + (i - lofs[b2])] = sv[i];
    }
}

__global__ __launch_bounds__(256) void bkt_build(const int* __restrict__ ebuf,
                                                 const int* __restrict__ boff,
                                                 int* __restrict__ row_ptr,
                                                 int* __restrict__ csr, int N) {
    __shared__ int lcnt[256];
    __shared__ int lofs[256];
    __shared__ int lcur[256];
    int t = threadIdx.x;
    int b = blockIdx.x;
    int base = b << 8;
    int ebeg = boff[b], eend = boff[b + 1];
    lcnt[t] = 0;
    __syncthreads();
    for (int e = ebeg + t; e < eend; e += 256)
        atomicAdd(&lcnt[((unsigned)ebuf[e]) >> 20], 1);
    __syncthreads();
    int v = lcnt[t];
    lofs[t] = v;
    __syncthreads();
    for (int off = 1; off < 256; off <<= 1) {
        int u = (t >= off) ? lofs[t - off] : 0;
        __syncthreads();
        lofs[t] += u;
        __syncthreads();
    }
    int ex = lofs[t] - v;
    __syncthreads();
    lofs[t] = ex;
    lcur[t] = 0;
    if (base + t < N) row_ptr[base + t] = ebeg + ex;
    __syncthreads();
    for (int e = ebeg + t; e < eend; e += 256) {
        int u = ebuf[e];
        int d = ((unsigned)u) >> 20;
        int r = atomicAdd(&lcur[d], 1);
        csr[ebeg + lofs[d] + r] = u & 0xFFFFF;
    }
}

// ================= mean aggregation over bf16 rows (R1-proven) =================

static __device__ __forceinline__ void acc8(uint4 v, float a[8]) {
    a[0] += bf_lo(v.x); a[1] += bf_hi(v.x);
    a[2] += bf_lo(v.y); a[3] += bf_hi(v.y);
    a[4] += bf_lo(v.z); a[5] += bf_hi(v.z);
    a[6] += bf_lo(v.w); a[7] += bf_hi(v.w);
}

static __device__ __forceinline__ uint4 grow(const ushort_t* __restrict__ xin,
                                             int s, int l16) {
    unsigned off = ((unsigned)s << 8) | ((unsigned)l16 << 4);  // bytes
    return *(const uint4*)((const char*)xin + off);
}

__global__ __launch_bounds__(256) void agg_b_kernel(const ushort_t* __restrict__ xin,
                                                    const int* __restrict__ csr,
                                                    const int* __restrict__ row_ptr,
                                                    ushort_t* __restrict__ aggb, int N) {
    int node = blockIdx.x * 4 + (threadIdx.x >> 6);
    if (node >= N) return;
    int lane = threadIdx.x & 63;
    int g = lane >> 4;    // row group 0..3
    int l16 = lane & 15;  // 16B segment within a 256B row
    int beg = row_ptr[node], end = row_ptr[node + 1];
    int deg = end - beg;
    float a[8] = {0.f, 0.f, 0.f, 0.f, 0.f, 0.f, 0.f, 0.f};

    if (deg > 0) {
        int deg64 = min(deg, 64);
        int myidx = csr[beg + min(lane, deg - 1)];  // one coalesced index load
        int e = 0;
        for (; e + 16 <= deg64; e += 16) {
            int s0 = __shfl(myidx, e + g);
            int s1 = __shfl(myidx, e + 4 + g);
            int s2 = __shfl(myidx, e + 8 + g);
            int s3 = __shfl(myidx, e + 12 + g);
            uint4 v0 = grow(xin, s0, l16);
            uint4 v1 = grow(xin, s1, l16);
            uint4 v2 = grow(xin, s2, l16);
            uint4 v3 = grow(xin, s3, l16);
            acc8(v0, a); acc8(v1, a); acc8(v2, a); acc8(v3, a);
        }
        if (e + 8 <= deg64) {
            int s0 = __shfl(myidx, e + g);
            int s1 = __shfl(myidx, e + 4 + g);
            uint4 v0 = grow(xin, s0, l16);
            uint4 v1 = grow(xin, s1, l16);
            acc8(v0, a); acc8(v1, a);
            e += 8;
        }
        if (e + 4 <= deg64) {
            int s0 = __shfl(myidx, e + g);
            uint4 v0 = grow(xin, s0, l16);
            acc8(v0, a);
            e += 4;
        }
        if (e < deg64) {  // masked tail
            int ee = min(e + g, deg64 - 1);
            int s = __shfl(myidx, ee);
            uint4 v = grow(xin, s, l16);
            if (e + g < deg64) acc8(v, a);
        }
        for (int e2 = 64; e2 < deg; e2 += 4) {  // rare deg>64 fallback
            int s = csr[beg + min(e2 + g, deg - 1)];
            uint4 v = grow(xin, s, l16);
            if (e2 + g < deg) acc8(v, a);
        }
    }

#pragma unroll
    for (int i = 0; i < 8; ++i) {
        a[i] += __shfl_xor(a[i], 16);
        a[i] += __shfl_xor(a[i], 32);
    }
    if (g == 0) {
        float inv = 1.0f / fmaxf((float)deg, 1.0f);
        uint4 o;
        o.x = (uint_t)f2bf(a[0] * inv) | ((uint_t)f2bf(a[1] * inv) << 16);
        o.y = (uint_t)f2bf(a[2] * inv) | ((uint_t)f2bf(a[3] * inv) << 16);
        o.z = (uint_t)f2bf(a[4] * inv) | ((uint_t)f2bf(a[5] * inv) << 16);
        o.w = (uint_t)f2bf(a[6] * inv) | ((uint_t)f2bf(a[7] * inv) << 16);
        unsigned off = ((unsigned)node << 8) | ((unsigned)l16 << 4);
        *(uint4*)((char*)aggb + off) = o;
    }
}

// ================= MFMA GEMM (R1-proven) =================

__global__ __launch_bounds__(256) void gemm_mfma(const ushort_t* __restrict__ Aagg,
                                                 const ushort_t* __restrict__ Ax,
                                                 const ushort_t* __restrict__ Wl,
                                                 const ushort_t* __restrict__ Wr,
                                                 const float* __restrict__ bias,
                                                 ushort_t* __restrict__ out_bf,
                                                 float* __restrict__ out_f32,
                                                 int N, int relu_bf) {
    __shared__ ushort_t sA[128 * 32];  // 8 KB
    __shared__ ushort_t sW[128 * 32];  // 8 KB
    int tid = threadIdx.x;
    int wave = tid >> 6, lane = tid & 63;
    int quad = lane >> 4, l15 = lane & 15;
    int wm = wave & 1, wc = wave >> 1;
    int n0 = blockIdx.x * 128;
    int sr = tid >> 2;
    int sseg = (tid & 3) * 8;

    f32x4 acc[4][4];
#pragma unroll
    for (int mt = 0; mt < 4; ++mt)
#pragma unroll
        for (int nt = 0; nt < 4; ++nt) acc[mt][nt] = (f32x4){0.f, 0.f, 0.f, 0.f};

    int ga0 = min(n0 + sr, N - 1);
    int ga1 = min(n0 + sr + 64, N - 1);

#pragma unroll
    for (int c = 0; c < 8; ++c) {
        const ushort_t* Ab = (c < 4) ? Aagg : Ax;
        const ushort_t* Wb = (c < 4) ? Wl : Wr;
        int koff = (c & 3) * 32 + sseg;
        bf16x8 va0 = *(const bf16x8*)(Ab + (size_t)ga0 * D + koff);
        bf16x8 va1 = *(const bf16x8*)(Ab + (size_t)ga1 * D + koff);
        bf16x8 vw0 = *(const bf16x8*)(Wb + (size_t)sr * D + koff);
        bf16x8 vw1 = *(const bf16x8*)(Wb + (size_t)(sr + 64) * D + koff);
        __syncthreads();
        *(bf16x8*)&sA[sr * 32 + sseg] = va0;
        *(bf16x8*)&sA[(sr + 64) * 32 + sseg] = va1;
        *(bf16x8*)&sW[sr * 32 + sseg] = vw0;
        *(bf16x8*)&sW[(sr + 64) * 32 + sseg] = vw1;
        __syncthreads();

        bf16x8 af[4], wf[4];
#pragma unroll
        for (int mt = 0; mt < 4; ++mt)
            af[mt] = *(const bf16x8*)&sA[(wm * 64 + mt * 16 + l15) * 32 + quad * 8];
#pragma unroll
        for (int nt = 0; nt < 4; ++nt)
            wf[nt] = *(const bf16x8*)&sW[(wc * 64 + nt * 16 + l15) * 32 + quad * 8];
#pragma unroll
        for (int mt = 0; mt < 4; ++mt)
#pragma unroll
            for (int nt = 0; nt < 4; ++nt)
                acc[mt][nt] = __builtin_amdgcn_mfma_f32_16x16x32_bf16(
                    af[mt], wf[nt], acc[mt][nt], 0, 0, 0);
    }

#pragma unroll
    for (int mt = 0; mt < 4; ++mt) {
#pragma unroll
        for (int nt = 0; nt < 4; ++nt) {
            int col = wc * 64 + nt * 16 + l15;
            float bv = bias[col];
#pragma unroll
            for (int reg = 0; reg < 4; ++reg) {
                int row = n0 + wm * 64 + mt * 16 + quad * 4 + reg;
                if (row < N) {
                    float v = acc[mt][nt][reg] + bv;
                    if (relu_bf) {
                        v = fmaxf(v, 0.f);
                        out_bf[(size_t)row * D + col] = f2bf(v);
                    } else {
                        out_f32[(size_t)row * D + col] = v;
                    }
                }
            }
        }
    }
}

// ================= launch =================

extern "C" void kernel_launch(void* const* d_in, const int* in_sizes, int n_in,
                              void* d_out, int out_size, void* d_ws, size_t ws_size,
                              hipStream_t stream) {
    const float* x   = (const float*)d_in[0];
    const int*   ei  = (const int*)d_in[1];
    const float* W1l = (const float*)d_in[2];
    const float* b1  = (const float*)d_in[3];
    const float* W1r = (const float*)d_in[4];
    const float* W2l = (const float*)d_in[5];
    const float* b2  = (const float*)d_in[6];
    const float* W2r = (const float*)d_in[7];
    float* out = (float*)d_out;

    int N = in_sizes[0] / D;
    int E = in_sizes[1] / 2;
    const int* src = ei;
    const int* dst = ei + E;

    char* ws = (char*)d_ws;
    size_t off = 0;
    auto take = [&](size_t bytes) -> char* {
        char* p = ws + off;
        off += (bytes + 255) & ~(size_t)255;
        return p;
    };
    int*      row_ptr = (int*)take((size_t)(N + 1) * sizeof(int));
    int*      bhist   = (int*)take((size_t)(512 + 512 + 513) * sizeof(int));
    int*      bcur    = bhist + 512;
    int*      boff    = bhist + 1024;
    int*      ebuf    = (int*)take((size_t)E * sizeof(int));
    int*      csr     = (int*)take((size_t)E * sizeof(int));
    ushort_t* xb      = (ushort_t*)take((size_t)N * D * sizeof(ushort_t));
    ushort_t* hb      = (ushort_t*)take((size_t)N * D * sizeof(ushort_t));
    ushort_t* aggb    = (ushort_t*)take((size_t)N * D * sizeof(ushort_t));
    ushort_t* W1lb    = (ushort_t*)take((size_t)D * D * sizeof(ushort_t));
    ushort_t* W1rb    = (ushort_t*)take((size_t)D * D * sizeof(ushort_t));
    ushort_t* W2lb    = (ushort_t*)take((size_t)D * D * sizeof(ushort_t));
    ushort_t* W2rb    = (ushort_t*)take((size_t)D * D * sizeof(ushort_t));
    (void)ws_size;
    (void)n_in;
    (void)out_size;

    hipMemsetAsync(bhist, 0, 1024 * sizeof(int), stream);

    int NB = (N + 255) / 256;
    int EB = (E + 4095) / 4096;
    long nx = (long)N * D;
    int CX = (int)((nx / 8 + 255) / 256);

    front_fused<<<EB + CX + 32, 256, 0, stream>>>(
        dst, bhist, E, EB, x, xb, nx, CX,
        W1l, W1r, W2l, W2r, W1lb, W1rb, W2lb, W2rb);
    bkt_scan<<<1, 512, 0, stream>>>(bhist, boff, bcur, row_ptr, N, E);
    bkt_scatter<<<EB, 256, 0, stream>>>(src, dst, bcur, ebuf, E);
    bkt_build<<<NB, 256, 0, stream>>>(ebuf, boff, row_ptr, csr, N);

    int ablocks = (N + 3) / 4;
    int gblocks = (N + 127) / 128;

    agg_b_kernel<<<ablocks, 256, 0, stream>>>(xb, csr, row_ptr, aggb, N);
    gemm_mfma<<<gblocks, 256, 0, stream>>>(aggb, xb, W1lb, W1rb, b1, hb, nullptr, N, 1);

    agg_b_kernel<<<ablocks, 256, 0, stream>>>(hb, csr, row_ptr, aggb, N);
    gemm_mfma<<<gblocks, 256, 0, stream>>>(aggb, hb, W2lb, W2rb, b2, nullptr, out, N, 0);
}